// Round 12
// baseline (839.391 us; speedup 1.0000x reference)
//
#include <hip/hip_runtime.h>
#include <hip/hip_fp16.h>
#include <math.h>

#define NN 100000
#define NE 800000
#define F 128
#define KK 256
#define OUTD 40
#define EPSF 1e-5f
#define NB 391   // ceil(NN/256)
#define LROWS 64 // rows per block in fused_layer
#define NLB 1563 // ceil(NN/64)

// ---------------- fp16 helpers (gather shadow copies) ----------------
union H4 {
  ushort4 u;
  _Float16 h[4];
};

__device__ __forceinline__ float4 ld_h4(const ushort* p) {
  H4 a;
  a.u = *(const ushort4*)p;
  float4 f;
  f.x = (float)a.h[0];
  f.y = (float)a.h[1];
  f.z = (float)a.h[2];
  f.w = (float)a.h[3];
  return f;
}

__device__ __forceinline__ ushort4 st_h4(const float4& v) {
  H4 a;
  a.h[0] = (_Float16)v.x;
  a.h[1] = (_Float16)v.y;
  a.h[2] = (_Float16)v.z;
  a.h[3] = (_Float16)v.w;
  return a.u;
}

// ---------------- edge_index dtype normalization ----------------
__global__ void detect_kernel(const int* __restrict__ ei_raw, int* __restrict__ flag) {
  __shared__ int any;
  if (threadIdx.x == 0) any = 0;
  __syncthreads();
  if (ei_raw[2 * threadIdx.x + 1] != 0) atomicOr(&any, 1);
  __syncthreads();
  if (threadIdx.x == 0) *flag = (any == 0) ? 1 : 0;  // 1 => int64 source
}

__global__ __launch_bounds__(256) void conv_kernel(const int* __restrict__ ei_raw,
                                                   const int* __restrict__ flag,
                                                   int* __restrict__ es) {
  int i = blockIdx.x * 256 + threadIdx.x;
  if (i < 2 * NE) {
    int f = *flag;
    es[i] = f ? ei_raw[2 * i] : ei_raw[i];
  }
}

// ---------------- x -> fp16 shadow ----------------
__global__ __launch_bounds__(256) void conv_x(const float* __restrict__ x,
                                              ushort* __restrict__ xh) {
  int i = blockIdx.x * 256 + threadIdx.x;  // NN*F/4 threads
  if (i < NN * F / 4) {
    float4 v = *(const float4*)(x + (size_t)i * 4);
    *(ushort4*)(xh + (size_t)i * 4) = st_h4(v);
  }
}

// ---------------- CSR build (dst-keyed, stores src) ----------------
__global__ __launch_bounds__(256) void deg_kernel(const int* __restrict__ dst,
                                                  int* __restrict__ deg) {
  int e = blockIdx.x * 256 + threadIdx.x;
  if (e < NE) atomicAdd(&deg[dst[e]], 1);
}

__global__ __launch_bounds__(256) void scan1(const int* __restrict__ deg,
                                             int* __restrict__ offs,
                                             int* __restrict__ bsum) {
  __shared__ int sh[256];
  const int tid = threadIdx.x;
  const int i = blockIdx.x * 256 + tid;
  int v = (i < NN) ? deg[i] : 0;
  sh[tid] = v;
  __syncthreads();
#pragma unroll
  for (int off = 1; off < 256; off <<= 1) {
    int add = (tid >= off) ? sh[tid - off] : 0;
    __syncthreads();
    sh[tid] += add;
    __syncthreads();
  }
  if (i < NN) offs[i] = sh[tid] - v;  // exclusive
  if (tid == 255) bsum[blockIdx.x] = sh[255];
}

__global__ void scan2(int* __restrict__ bsum) {
  __shared__ int sh[512];
  const int t = threadIdx.x;
  int v = (t < NB) ? bsum[t] : 0;
  sh[t] = v;
  __syncthreads();
#pragma unroll
  for (int off = 1; off < 512; off <<= 1) {
    int add = (t >= off) ? sh[t - off] : 0;
    __syncthreads();
    sh[t] += add;
    __syncthreads();
  }
  if (t < NB) bsum[t] = sh[t] - v;  // exclusive block offsets
}

__global__ __launch_bounds__(256) void scan3(int* __restrict__ offs,
                                             int* __restrict__ woff,
                                             const int* __restrict__ bsum) {
  int i = blockIdx.x * 256 + threadIdx.x;
  if (i < NN) {
    int o = offs[i] + bsum[blockIdx.x];
    offs[i] = o;
    woff[i] = o;
  }
  if (i == 0) offs[NN] = NE;
}

__global__ __launch_bounds__(256) void fill_kernel(const int* __restrict__ src,
                                                   const int* __restrict__ dst,
                                                   int* __restrict__ woff,
                                                   int* __restrict__ eidx) {
  int e = blockIdx.x * 256 + threadIdx.x;
  if (e < NE) {
    int pos = atomicAdd(&woff[dst[e]], 1);
    eidx[pos] = src[e];
  }
}

// ---------------- W4 transpose: Wt[j][k] over concat-K ----------------
__global__ __launch_bounds__(256) void transpose_w(const float* __restrict__ Wl,
                                                   const float* __restrict__ Wr,
                                                   float* __restrict__ Wt) {
  int i = blockIdx.x * 256 + threadIdx.x;  // OUTD*KK
  if (i < OUTD * KK) {
    int j = i / KK, k = i - j * KK;
    Wt[i] = (k < F) ? Wl[k * OUTD + j] : Wr[(k - F) * OUTD + j];
  }
}

// ---------------- shared helpers ----------------
__device__ __forceinline__ void bnrelu4(float4& v, const float4& s, const float4& b) {
  v.x = fmaxf(fmaf(v.x, s.x, b.x), 0.f);
  v.y = fmaxf(fmaf(v.y, s.y, b.y), 0.f);
  v.z = fmaxf(fmaf(v.z, s.z, b.z), 0.f);
  v.w = fmaxf(fmaf(v.w, s.w, b.w), 0.f);
}

// gather-mean of one row's edge list (fp16 source rows), 8-deep ILP.
template <int BN>
__device__ __forceinline__ void gather_row(const ushort* __restrict__ hinh,
                                           const int* __restrict__ eidx,
                                           int beg, int end, int q,
                                           const float4& scl, const float4& shf,
                                           float4& out) {
  float ax = 0.f, ay = 0.f, az = 0.f, aw = 0.f;
  int i = beg;
  for (; i + 8 <= end; i += 8) {
    int s0 = eidx[i],     s1 = eidx[i + 1], s2 = eidx[i + 2], s3 = eidx[i + 3];
    int s4 = eidx[i + 4], s5 = eidx[i + 5], s6 = eidx[i + 6], s7 = eidx[i + 7];
    ushort4 w0 = *(const ushort4*)(hinh + (size_t)s0 * F + q * 4);
    ushort4 w1 = *(const ushort4*)(hinh + (size_t)s1 * F + q * 4);
    ushort4 w2 = *(const ushort4*)(hinh + (size_t)s2 * F + q * 4);
    ushort4 w3 = *(const ushort4*)(hinh + (size_t)s3 * F + q * 4);
    ushort4 w4 = *(const ushort4*)(hinh + (size_t)s4 * F + q * 4);
    ushort4 w5 = *(const ushort4*)(hinh + (size_t)s5 * F + q * 4);
    ushort4 w6 = *(const ushort4*)(hinh + (size_t)s6 * F + q * 4);
    ushort4 w7 = *(const ushort4*)(hinh + (size_t)s7 * F + q * 4);
#define ACCU(ww)                                       \
  do {                                                 \
    H4 a_; a_.u = ww;                                  \
    float4 vv;                                         \
    vv.x = (float)a_.h[0]; vv.y = (float)a_.h[1];      \
    vv.z = (float)a_.h[2]; vv.w = (float)a_.h[3];      \
    if (BN) bnrelu4(vv, scl, shf);                     \
    ax += vv.x; ay += vv.y; az += vv.z; aw += vv.w;    \
  } while (0)
    ACCU(w0); ACCU(w1); ACCU(w2); ACCU(w3);
    ACCU(w4); ACCU(w5); ACCU(w6); ACCU(w7);
  }
  for (; i < end; ++i) {
    int s0 = eidx[i];
    ushort4 w0 = *(const ushort4*)(hinh + (size_t)s0 * F + q * 4);
    ACCU(w0);
  }
#undef ACCU
  float m = 1.0f / fmaxf((float)(end - beg), 1.0f);
  out.x = ax * m; out.y = ay * m; out.z = az * m; out.w = aw * m;
}

// one K=128 FMA half over a 64-row tile: acc[8][4] += tile @ Wp
__device__ __forceinline__ void fma_half64(const float (*tile)[F],
                                           const float* __restrict__ Wp,
                                           int tx, int ty, float acc[8][4]) {
  for (int k = 0; k < F; k += 4) {
    float4 in4[8];
#pragma unroll
    for (int r = 0; r < 8; ++r)
      in4[r] = *(const float4*)(&tile[ty * 8 + r][k]);
#pragma unroll
    for (int i = 0; i < 4; ++i) {
      float4 w = *(const float4*)(Wp + (size_t)(k + i) * F + tx * 4);
      float a[8];
#pragma unroll
      for (int r = 0; r < 8; ++r) a[r] = ((const float*)&in4[r])[i];
#pragma unroll
      for (int r = 0; r < 8; ++r) {
        acc[r][0] = fmaf(a[r], w.x, acc[r][0]);
        acc[r][1] = fmaf(a[r], w.y, acc[r][1]);
        acc[r][2] = fmaf(a[r], w.z, acc[r][2]);
        acc[r][3] = fmaf(a[r], w.w, acc[r][3]);
      }
    }
  }
}

// ------ fused layer (64-row tile): fp16 gather-mean + dual GEMM + BN-stats ---
// Gather reads the fp16 shadow (halved random-fetch bytes); root reads fp32.
// Epilogue writes BOTH fp32 (root/stats source) and fp16 (next gather) rows.
// No inter-phase barriers: each half-wave group owns tile rows 8g..8g+7.
template <int BN>
__global__ __launch_bounds__(256) void fused_layer(const float* __restrict__ hin,
                                                   const ushort* __restrict__ hinh,
                                                   const int* __restrict__ eidx,
                                                   const int* __restrict__ offs,
                                                   const float* __restrict__ sc,
                                                   const float* __restrict__ Wl,
                                                   const float* __restrict__ bl,
                                                   const float* __restrict__ Wr,
                                                   float* __restrict__ out,
                                                   ushort* __restrict__ outh,
                                                   float* __restrict__ sums) {
  __shared__ float tile[LROWS][F];  // 32 KB
  const int t = threadIdx.x;
  const int row0 = blockIdx.x * LROWS;
  const int q = t & 31;
  const int grp = t >> 5;  // 8 groups x 8 rows
  float4 scl, shf;
  if (BN) {
    scl = *(const float4*)(sc + q * 4);
    shf = *(const float4*)(sc + 128 + q * 4);
  }

  // phase A: gather-mean 8 rows (own rows only, fp16 source)
#pragma unroll 1
  for (int rr = 0; rr < 8; ++rr) {
    int r = grp * 8 + rr;
    int n = row0 + r;
    float4 o = {0.f, 0.f, 0.f, 0.f};
    if (n < NN) {
      int beg = offs[n];
      int end = offs[n + 1];
      gather_row<BN>(hinh, eidx, beg, end, q, scl, shf, o);
    }
    *(float4*)(&tile[r][q * 4]) = o;
  }
  // no barrier: intra-wave LDS dependency

  const int tx = t & 31;
  const int ty = t >> 5;
  float acc[8][4];
#pragma unroll
  for (int r = 0; r < 8; ++r)
#pragma unroll
    for (int c = 0; c < 4; ++c) acc[r][c] = 0.f;

  fma_half64(tile, Wl, tx, ty, acc);

  // phase B: root rows (fp32, own rows only)
#pragma unroll
  for (int rr = 0; rr < 8; ++rr) {
    int r = grp * 8 + rr;
    int row = row0 + r;
    float4 v = {0.f, 0.f, 0.f, 0.f};
    if (row < NN) {
      v = *(const float4*)(hin + (size_t)row * F + q * 4);
      if (BN) bnrelu4(v, scl, shf);
    }
    *(float4*)(&tile[r][q * 4]) = v;
  }

  fma_half64(tile, Wr, tx, ty, acc);

  float4 b4 = *(const float4*)(bl + tx * 4);
  float ps[4] = {0.f, 0.f, 0.f, 0.f};
  float pq[4] = {0.f, 0.f, 0.f, 0.f};
#pragma unroll
  for (int r = 0; r < 8; ++r) {
    int row = row0 + ty * 8 + r;
    if (row < NN) {
      float4 o;
      o.x = acc[r][0] + b4.x;
      o.y = acc[r][1] + b4.y;
      o.z = acc[r][2] + b4.z;
      o.w = acc[r][3] + b4.w;
      ps[0] += o.x; pq[0] = fmaf(o.x, o.x, pq[0]);
      ps[1] += o.y; pq[1] = fmaf(o.y, o.y, pq[1]);
      ps[2] += o.z; pq[2] = fmaf(o.z, o.z, pq[2]);
      ps[3] += o.w; pq[3] = fmaf(o.w, o.w, pq[3]);
      *(float4*)(out + (size_t)row * F + tx * 4) = o;
      *(ushort4*)(outh + (size_t)row * F + tx * 4) = st_h4(o);
    }
  }
  // BN-stats epilogue: tile reused as CROSS-WAVE scratch -> barriers required
  __syncthreads();
  float* red = &tile[0][0];  // [2][8][128] floats = 8 KB
#pragma unroll
  for (int j = 0; j < 4; ++j) {
    red[ty * 128 + tx * 4 + j] = ps[j];
    red[2048 + ty * 128 + tx * 4 + j] = pq[j];
  }
  __syncthreads();
  if (t < 128) {
    float s = 0.f, qq = 0.f;
#pragma unroll
    for (int g2 = 0; g2 < 8; ++g2) {
      s += red[g2 * 128 + t];
      qq += red[2048 + g2 * 128 + t];
    }
    atomicAdd(&sums[t], s);
    atomicAdd(&sums[128 + t], qq);
  }
}

// ---------------- BN parameter computation ----------------
__global__ void bn_params(const float* __restrict__ sums, const float* __restrict__ g,
                          const float* __restrict__ b, float* __restrict__ sc) {
  int c = threadIdx.x;  // 128
  float mu = sums[c] * (1.0f / NN);
  float var = sums[128 + c] * (1.0f / NN) - mu * mu;
  float scale = g[c] * rsqrtf(var + EPSF);
  sc[c] = scale;
  sc[128 + c] = b[c] - mu * scale;
}

// ------ fused final: fp16 gather-mean + [K=256 -> 40] GEMM + log_softmax -----
__global__ __launch_bounds__(256) void fused_final(const float* __restrict__ hin,
                                                   const ushort* __restrict__ hinh,
                                                   const int* __restrict__ eidx,
                                                   const int* __restrict__ offs,
                                                   const float* __restrict__ sc,
                                                   const float* __restrict__ Wt,
                                                   const float* __restrict__ bl,
                                                   float* __restrict__ out) {
  __shared__ float tile[32][F];  // 16 KB
  const int t = threadIdx.x;
  const int row0 = blockIdx.x * 32;
  const int q = t & 31;
  const int grp = t >> 5;
  float4 scl = *(const float4*)(sc + q * 4);
  float4 shf = *(const float4*)(sc + 128 + q * 4);

#pragma unroll 1
  for (int rr = 0; rr < 4; ++rr) {
    int r = grp * 4 + rr;
    int n = row0 + r;
    int beg = offs[n];
    int end = offs[n + 1];
    float4 o;
    gather_row<1>(hinh, eidx, beg, end, q, scl, shf, o);
    *(float4*)(&tile[r][q * 4]) = o;
  }
  // no barrier: intra-wave

  const int tx = t & 63;   // output column (40 active)
  const int wv = t >> 6;   // wave id: rows wv*8 .. wv*8+7
  const int jj = (tx < OUTD) ? tx : 0;
  const float* __restrict__ wrow = Wt + (size_t)jj * KK;
  float acc[8] = {0.f, 0.f, 0.f, 0.f, 0.f, 0.f, 0.f, 0.f};
#pragma unroll 2
  for (int k = 0; k < F; k += 4) {
    float4 w = *(const float4*)(wrow + k);
#pragma unroll
    for (int r = 0; r < 8; ++r) {
      float4 a = *(const float4*)(&tile[wv * 8 + r][k]);  // wave-uniform broadcast
      acc[r] = fmaf(a.x, w.x, acc[r]);
      acc[r] = fmaf(a.y, w.y, acc[r]);
      acc[r] = fmaf(a.z, w.z, acc[r]);
      acc[r] = fmaf(a.w, w.w, acc[r]);
    }
  }

#pragma unroll
  for (int rr = 0; rr < 4; ++rr) {
    int r = grp * 4 + rr;
    float4 v = *(const float4*)(hin + (size_t)(row0 + r) * F + q * 4);
    bnrelu4(v, scl, shf);
    *(float4*)(&tile[r][q * 4]) = v;
  }

#pragma unroll 2
  for (int k = 0; k < F; k += 4) {
    float4 w = *(const float4*)(wrow + F + k);
#pragma unroll
    for (int r = 0; r < 8; ++r) {
      float4 a = *(const float4*)(&tile[wv * 8 + r][k]);
      acc[r] = fmaf(a.x, w.x, acc[r]);
      acc[r] = fmaf(a.y, w.y, acc[r]);
      acc[r] = fmaf(a.z, w.z, acc[r]);
      acc[r] = fmaf(a.w, w.w, acc[r]);
    }
  }

  float bias = bl[jj];
#pragma unroll
  for (int r = 0; r < 8; ++r) {
    float v = acc[r] + bias;
    float m = (tx < OUTD) ? v : -INFINITY;
#pragma unroll
    for (int off = 32; off > 0; off >>= 1) m = fmaxf(m, __shfl_xor(m, off));
    float e = (tx < OUTD) ? expf(v - m) : 0.f;
    float s = e;
#pragma unroll
    for (int off = 32; off > 0; off >>= 1) s += __shfl_xor(s, off);
    if (tx < OUTD) out[(size_t)(row0 + wv * 8 + r) * OUTD + tx] = v - m - logf(s);
  }
}

// ---------------- driver ----------------
extern "C" void kernel_launch(void* const* d_in, const int* in_sizes, int n_in,
                              void* d_out, int out_size, void* d_ws, size_t ws_size,
                              hipStream_t stream) {
  const float* x = (const float*)d_in[0];
  const int* ei_raw = (const int*)d_in[1];
  const float* Wl[4] = {(const float*)d_in[2], (const float*)d_in[5],
                        (const float*)d_in[8], (const float*)d_in[11]};
  const float* bl[4] = {(const float*)d_in[3], (const float*)d_in[6],
                        (const float*)d_in[9], (const float*)d_in[12]};
  const float* Wr[4] = {(const float*)d_in[4], (const float*)d_in[7],
                        (const float*)d_in[10], (const float*)d_in[13]};
  const float* g[3] = {(const float*)d_in[14], (const float*)d_in[16],
                       (const float*)d_in[18]};
  const float* bb[3] = {(const float*)d_in[15], (const float*)d_in[17],
                        (const float*)d_in[19]};

  char* wsb = (char*)d_ws;
  float* hA   = (float*)wsb;                      wsb += (size_t)NN * F * 4;
  float* hB   = (float*)wsb;                      wsb += (size_t)NN * F * 4;
  ushort* xh  = (ushort*)wsb;                     wsb += (size_t)NN * F * 2;
  ushort* hAh = (ushort*)wsb;                     wsb += (size_t)NN * F * 2;
  ushort* hBh = (ushort*)wsb;                     wsb += (size_t)NN * F * 2;
  int* es    = (int*)wsb;                         wsb += (size_t)2 * NE * 4;
  int* eidx  = (int*)wsb;                         wsb += (size_t)NE * 4;
  int* offs  = (int*)wsb;                         wsb += (size_t)(NN + 64) * 4;
  int* woff  = (int*)wsb;                         wsb += (size_t)(NN + 64) * 4;
  int* bsum  = (int*)wsb;                         wsb += 512 * 4;
  float* sums = (float*)wsb;                      wsb += 256 * 4;
  float* sc   = (float*)wsb;                      wsb += 256 * 4;
  float* Wt   = (float*)wsb;                      wsb += (size_t)OUTD * KK * 4;
  int* flag   = (int*)wsb;                        wsb += 256;

  int* esrc = es;
  int* edst = es + NE;

  // --- edge_index normalization (int64 vs int32) + x fp16 shadow ---
  detect_kernel<<<1, 256, 0, stream>>>(ei_raw, flag);
  conv_kernel<<<(2 * NE + 255) / 256, 256, 0, stream>>>(ei_raw, flag, es);
  conv_x<<<(NN * F / 4 + 255) / 256, 256, 0, stream>>>(x, xh);

  // --- CSR build (dst-keyed) + W4 transpose ---
  hipMemsetAsync(woff, 0, NN * sizeof(int), stream);
  deg_kernel<<<NE / 256, 256, 0, stream>>>(edst, woff);
  scan1<<<NB, 256, 0, stream>>>(woff, offs, bsum);
  scan2<<<1, 512, 0, stream>>>(bsum);
  scan3<<<NB, 256, 0, stream>>>(offs, woff, bsum);
  fill_kernel<<<NE / 256, 256, 0, stream>>>(esrc, edst, woff, eidx);
  transpose_w<<<(OUTD * KK + 255) / 256, 256, 0, stream>>>(Wl[3], Wr[3], Wt);

  const float* cur = x;
  const ushort* curh = xh;
  float* bufs[2] = {hA, hB};
  ushort* bufsh[2] = {hAh, hBh};
  for (int L = 0; L < 3; ++L) {
    float* hpre = bufs[L & 1];
    ushort* hpreh = bufsh[L & 1];
    hipMemsetAsync(sums, 0, 256 * sizeof(float), stream);
    if (L == 0)
      fused_layer<0><<<NLB, 256, 0, stream>>>(cur, curh, eidx, offs, nullptr, Wl[L],
                                              bl[L], Wr[L], hpre, hpreh, sums);
    else
      fused_layer<1><<<NLB, 256, 0, stream>>>(cur, curh, eidx, offs, sc, Wl[L], bl[L],
                                              Wr[L], hpre, hpreh, sums);
    bn_params<<<1, 128, 0, stream>>>(sums, g[L], bb[L], sc);
    cur = hpre;
    curh = hpreh;
  }
  // layer 4 + log_softmax (both BN applications fused in-kernel)
  fused_final<<<NN / 32, 256, 0, stream>>>(cur, curh, eidx, offs, sc, Wt, bl[3],
                                           (float*)d_out);
}